// Round 1
// baseline (425.763 us; speedup 1.0000x reference)
//
#include <hip/hip_runtime.h>

// CRF Viterbi decode (B=512, T=512, S=64).
// R10: ONE WAVE PER BATCH — the cross-wave rendezvous is gone entirely.
//
// R9 (4 waves x 16-prev slices) measured ~1315 cy/step, of which only ~210 cy
// was VALU issue; the rest was the per-step rendezvous (tree -> ds_write ->
// lgkmcnt -> s_barrier -> ds_read ~120cy -> merge). Since all 512 blocks are
// co-resident, total time == one block's serial step latency, so the only
// lever is the chain itself. A single wave doing the full 64-prev reduction
// via 64 literal-lane readlanes trades ~+250 cy of extra issue for ~-600 cy
// of barrier/LDS round-trip per step.
//
// Layout: lane n owns tag n; its full transitions row trans[n][0..63] lives
// in 64 VGPRs. Per step: cand_p = readlane(fv,p) + tr[p] over 8 independent
// chains of 8 (strict >, ascending p => first-argmax, exact jnp semantics),
// then a left-priority merge tree. fmaxf on ties keeps the identical value.
// Wave packs 4 backpointers/dword into LDS (32KB) and runs the same
// validated backtrace as R9. 512 blocks x 64 threads -> 2 single-wave blocks
// per CU, each wave alone on a SIMD: no issue contention, no barriers.
// Output: out[0..B) = path_score, out[B + b*(T-1) + t] = (float)tag.

constexpr int Bz = 512;
constexpr int Tz = 512;
constexpr int Sz = 64;
constexpr float NEGINF = -10000.0f;

__device__ __forceinline__ float rlf(float x, int lane) {
    return __int_as_float(__builtin_amdgcn_readlane(__float_as_int(x), lane));
}

__global__ __launch_bounds__(64)
void crf_viterbi_kernel(const float* __restrict__ logits,
                        const float* __restrict__ masks,
                        const float* __restrict__ trans,
                        float* __restrict__ out)
{
    const int n = threadIdx.x;       // lane id == tag id
    const int b = blockIdx.x;        // one batch element per (single-wave) block

    __shared__ unsigned bp[128 * 64];   // packed backpointers, 4 steps/dword, 32 KB
    __shared__ float ys[Tz - 1];        // emitted tags (backtrace)

    // full transitions row for this lane's tag: tr[p] = trans[n][p]
    float tr[64];
    {
        const float4* tr4 = reinterpret_cast<const float4*>(trans + (size_t)n * Sz);
        #pragma unroll
        for (int k = 0; k < 16; ++k) {
            float4 t = tr4[k];
            tr[4 * k + 0] = t.x; tr[4 * k + 1] = t.y;
            tr[4 * k + 2] = t.z; tr[4 * k + 3] = t.w;
        }
    }

    float fv = (n == 0) ? 0.0f : NEGINF;

    const float* lgbase = logits + (size_t)b * Tz * Sz;
    const float* mkbase = masks + (size_t)b * Tz;

    // group-of-4 software-pipelined prefetch (2 groups deep)
    float lgc[4], lgn[4], mkc[4], mkn[4];
    #pragma unroll
    for (int k = 0; k < 4; ++k) {
        lgc[k] = lgbase[(1 + k) * Sz + n];
        mkc[k] = mkbase[1 + k];
        lgn[k] = lgbase[(5 + k) * Sz + n];
        mkn[k] = mkbase[5 + k];
    }

    unsigned pk = 0;

    // ---- one Viterbi step (compile-time k => literal lanes everywhere) ----
    auto step = [&](int k, float lg, float mk) -> float {
        // 8 independent running chains over prevs (8 each). Within a chain:
        // ascending p with strict > keeps the EARLIEST p on ties; fmaxf on a
        // tie selects the identical value. Exact jnp first-argmax.
        float m[8]; int id[8];
        #pragma unroll
        for (int c = 0; c < 8; ++c) {
            m[c]  = rlf(fv, 8 * c) + tr[8 * c];
            id[c] = 8 * c;
            #pragma unroll
            for (int j = 1; j < 8; ++j) {
                const int p = 8 * c + j;
                float cand = rlf(fv, p) + tr[p];
                bool g = cand > m[c];          // uses OLD m[c]
                id[c] = g ? p : id[c];
                m[c]  = fmaxf(m[c], cand);
            }
        }
        // merge 8 chain results, left priority on ties (strict >)
        #pragma unroll
        for (int st = 1; st < 8; st <<= 1) {
            #pragma unroll
            for (int c = 0; c < 8; c += 2 * st) {
                bool g = m[c + st] > m[c];
                id[c] = g ? id[c + st] : id[c];
                m[c]  = fmaxf(m[c], m[c + st]);
            }
        }
        pk |= ((unsigned)id[0]) << (8 * k);
        float mm = m[0];
        fv = mm + lg * mk;                     // mask multiplies emission only
        return mm;                             // pre-feat max (for path_score)
    };

    // main: groups g = 0..126 cover steps i = 4g+k (i <= 507)
    for (int g = 0; g < 127; ++g) {
        step(0, lgc[0], mkc[0]);
        step(1, lgc[1], mkc[1]);
        step(2, lgc[2], mkc[2]);
        step(3, lgc[3], mkc[3]);

        bp[g * 64 + n] = pk;                   // 64 consecutive dwords: conflict-free
        pk = 0;

        // rotate prefetch; issue loads for group g+2 (rows 4g+9 .. 4g+12)
        #pragma unroll
        for (int k = 0; k < 4; ++k) { lgc[k] = lgn[k]; mkc[k] = mkn[k]; }
        #pragma unroll
        for (int k = 0; k < 4; ++k) {
            int t = 4 * g + 9 + k;
            t = (t < Tz) ? t : (Tz - 1);
            lgn[k] = lgbase[t * Sz + n];
            mkn[k] = mkbase[t];
        }
    }

    // tail: steps 508, 509, 510 (group 127, k = 0..2)
    step(0, lgc[0], mkc[0]);
    step(1, lgc[1], mkc[1]);
    float psc = step(2, lgc[2], mkc[2]);
    bp[127 * 64 + n] = pk;                     // flush steps 508..510
    if (n == 63) out[b] = psc;                 // path_score = vmaxs[-1][:,63]

    // ---- backtrace (intra-wave; same-wave DS ops complete in order) ----
    unsigned wcur = bp[127 * 64 + n];
    int w127_63 = __builtin_amdgcn_readlane((int)wcur, 63);
    int tag = (w127_63 >> 16) & 255;           // t0 = bptrs[510][63]

    for (int g = 127; g >= 0; --g) {
        unsigned wnext = (g > 0) ? bp[(g - 1) * 64 + n] : 0u;  // prefetch
        const int smax = (g == 127) ? 2 : 3;
        for (int s = smax; s >= 0; --s) {
            int idx = 4 * g + s;
            if (n == 0) ys[idx] = (float)tag;  // emit BEFORE following ptr
            int wd = __builtin_amdgcn_readlane((int)wcur, tag);  // tag is uniform
            tag = (wd >> (8 * s)) & 255;
        }
        wcur = wnext;
    }

    __syncthreads();                           // single wave: trivial; orders ys
    float* outseq = out + Bz + (size_t)b * (Tz - 1);
    for (int k = n; k < Tz - 1; k += 64) outseq[k] = ys[k];
}

extern "C" void kernel_launch(void* const* d_in, const int* in_sizes, int n_in,
                              void* d_out, int out_size, void* d_ws, size_t ws_size,
                              hipStream_t stream) {
    const float* logits = (const float*)d_in[0];
    const float* masks  = (const float*)d_in[1];
    const float* trans  = (const float*)d_in[2];
    float* out = (float*)d_out;
    (void)in_sizes; (void)n_in; (void)out_size; (void)d_ws; (void)ws_size;

    crf_viterbi_kernel<<<dim3(Bz), dim3(64), 0, stream>>>(logits, masks, trans, out);
}